// Round 14
// baseline (105.912 us; speedup 1.0000x reference)
//
#include <hip/hip_runtime.h>
#include <stdint.h>

using bf16x8 = __attribute__((ext_vector_type(8))) short;
using f32x4  = __attribute__((ext_vector_type(4))) float;

#define DEVINL __device__ __forceinline__

DEVINL unsigned short f2bf(float f) {
  union { float f; unsigned u; } v; v.f = f;
  unsigned u = v.u;
  return (unsigned short)((u + 0x7FFFu + ((u >> 16) & 1u)) >> 16);
}
DEVINL float bf2f(unsigned short h) {
  union { unsigned u; float f; } v; v.u = ((unsigned)h) << 16;
  return v.f;
}

DEVINL void gload_lds16(const void* g, void* l) {
  __builtin_amdgcn_global_load_lds(
      (const __attribute__((address_space(1))) void*)g,
      (__attribute__((address_space(3))) void*)l, 16, 0, 0);
}

// ---------------------------------------------------------------------------
// 8-phase-style core (T3+T4+T5 on the r12 geometry): 256x128 bf16 tile,
// 8 waves (4M x 2N), BK=64, depth-3 slot ring (144 KB LDS; occupancy
// unchanged vs r12 which was already 1 blk/CU), counted vmcnt(12/6/0) once
// per K-tile, 4 phases/K-tile {8ds+8mfma},{8ds+8mfma},{8mfma},{8mfma} with
// raw s_barrier between and s_setprio(1) around MFMA clusters.
// T2 XOR swizzle via pre-swizzled GLOBAL source (LDS dest linear; bank
// conflicts measured 0 in r8/r12).
// Hazard invariants (superset of proven r12): slot kt%3 overwritten only by
// iter kt+1's STAGE, which follows iter kt's trailing barrier; slot kt read
// only after own-vmcnt + barrier.
// ---------------------------------------------------------------------------
template<int OUT_BF16, int HAS_BIAS>
DEVINL void gemm_core(const unsigned short* __restrict__ A,
                      const unsigned short* __restrict__ B,
                      void* __restrict__ C,
                      const float* __restrict__ bias,
                      int K, int Cld, int arow0, int brow0, int crow0, int ccol0)
{
  __shared__ __align__(16) unsigned short As[3][256 * 64];   // 96 KB
  __shared__ __align__(16) unsigned short Bs[3][128 * 64];   // 48 KB

  const int t    = threadIdx.x;        // 0..511
  const int wave = t >> 6;             // 0..7
  const int lane = t & 63;
  const int wr   = (wave >> 1) << 6;   // 0,64,128,192
  const int wc   = (wave & 1) << 6;    // 0,64
  const int lrow = lane & 15;
  const int kg   = lane >> 4;          // 0..3

  f32x4 acc[4][4];
#pragma unroll
  for (int r = 0; r < 4; ++r)
#pragma unroll
    for (int q = 0; q < 4; ++q) acc[r][q] = (f32x4){0.f, 0.f, 0.f, 0.f};

  // staging: 512 thr x 16B = 8 KB/pass; A: 4 passes, B: 2 passes.
  // pre-swizzled global source chunk: chunk_phys = chunk ^ (row&7).
  const int srow = t >> 3;                                  // 0..63
  const int scol = (((t & 7) ^ (srow & 7)) << 3);
  const unsigned short* aSrc = A + (size_t)(arow0 + srow) * K + scol;
  const unsigned short* bSrc = B + (size_t)(brow0 + srow) * K + scol;

  auto STAGE = [&](int slot, int kt) {
    const int k0 = kt << 6;
    char* aD = (char*)As[slot] + wave * 1024;
    char* bD = (char*)Bs[slot] + wave * 1024;
#pragma unroll
    for (int p = 0; p < 4; ++p)
      gload_lds16(aSrc + (size_t)(p * 64) * K + k0, aD + p * 8192);
#pragma unroll
    for (int p = 0; p < 2; ++p)
      gload_lds16(bSrc + (size_t)(p * 64) * K + k0, bD + p * 8192);
  };

  const int nt = K >> 6;               // >= 8 at all call sites
  STAGE(0, 0);
  STAGE(1, 1);

  // swizzled read chunk offsets (elements): chunk = (kg + kk/8) ^ (row&7)
  const int rs = lrow & 7;
  const int cA0 = ((kg + 0) ^ rs) << 3;   // kk = 0
  const int cA1 = ((kg + 4) ^ rs) << 3;   // kk = 32

  int sl = 0;                          // slot of tile kt
  for (int kt = 0; kt < nt; ++kt) {
    const unsigned short* Ab = As[sl];
    const unsigned short* Bb = Bs[sl];
    if (kt + 2 < nt) {
      int s2 = sl + 2; if (s2 >= 3) s2 -= 3;
      STAGE(s2, kt + 2);               // writes slot (kt-1)%3: safe after prev trailing barrier
      asm volatile("s_waitcnt vmcnt(12)" ::: "memory");   // own kt loads landed
    } else if (kt + 1 < nt) {
      asm volatile("s_waitcnt vmcnt(6)" ::: "memory");
    } else {
      asm volatile("s_waitcnt vmcnt(0)" ::: "memory");
    }
    __builtin_amdgcn_s_barrier();      // all waves' kt loads landed

    bf16x8 a0[4], b0[4], a1[4], b1[4];
    // ---- phase A: kk=0 reads + MFMA r0,r1
#pragma unroll
    for (int r = 0; r < 4; ++r)
      a0[r] = *(const bf16x8*)&Ab[(wr + r * 16 + lrow) * 64 + cA0];
#pragma unroll
    for (int q = 0; q < 4; ++q)
      b0[q] = *(const bf16x8*)&Bb[(wc + q * 16 + lrow) * 64 + cA0];
    __builtin_amdgcn_s_setprio(1);
#pragma unroll
    for (int r = 0; r < 2; ++r)
#pragma unroll
      for (int q = 0; q < 4; ++q)
        acc[r][q] = __builtin_amdgcn_mfma_f32_16x16x32_bf16(a0[r], b0[q], acc[r][q], 0, 0, 0);
    __builtin_amdgcn_s_setprio(0);
    __builtin_amdgcn_s_barrier();
    // ---- phase B: kk=32 reads + MFMA r2,r3 @ kk=0
#pragma unroll
    for (int r = 0; r < 4; ++r)
      a1[r] = *(const bf16x8*)&Ab[(wr + r * 16 + lrow) * 64 + cA1];
#pragma unroll
    for (int q = 0; q < 4; ++q)
      b1[q] = *(const bf16x8*)&Bb[(wc + q * 16 + lrow) * 64 + cA1];
    __builtin_amdgcn_s_setprio(1);
#pragma unroll
    for (int r = 2; r < 4; ++r)
#pragma unroll
      for (int q = 0; q < 4; ++q)
        acc[r][q] = __builtin_amdgcn_mfma_f32_16x16x32_bf16(a0[r], b0[q], acc[r][q], 0, 0, 0);
    __builtin_amdgcn_s_setprio(0);
    __builtin_amdgcn_s_barrier();
    // ---- phase C: MFMA r0,r1 @ kk=32
    __builtin_amdgcn_s_setprio(1);
#pragma unroll
    for (int r = 0; r < 2; ++r)
#pragma unroll
      for (int q = 0; q < 4; ++q)
        acc[r][q] = __builtin_amdgcn_mfma_f32_16x16x32_bf16(a1[r], b1[q], acc[r][q], 0, 0, 0);
    __builtin_amdgcn_s_setprio(0);
    __builtin_amdgcn_s_barrier();
    // ---- phase D: MFMA r2,r3 @ kk=32
    __builtin_amdgcn_s_setprio(1);
#pragma unroll
    for (int r = 2; r < 4; ++r)
#pragma unroll
      for (int q = 0; q < 4; ++q)
        acc[r][q] = __builtin_amdgcn_mfma_f32_16x16x32_bf16(a1[r], b1[q], acc[r][q], 0, 0, 0);
    __builtin_amdgcn_s_setprio(0);
    __builtin_amdgcn_s_barrier();      // trailing: slot sl free for overwrite
    ++sl; if (sl == 3) sl = 0;
  }

  // epilogue: C/D layout col=lane&15, row=(lane>>4)*4+v  [m89/m91 verified]
#pragma unroll
  for (int r = 0; r < 4; ++r) {
#pragma unroll
    for (int q = 0; q < 4; ++q) {
      const int col = ccol0 + wc + q * 16 + lrow;
      const float bv = HAS_BIAS ? bias[col] : 0.f;
#pragma unroll
      for (int v = 0; v < 4; ++v) {
        const int row = crow0 + wr + r * 16 + (kg << 2) + v;
        const float val = acc[r][q][v] + bv;
        if (OUT_BF16)
          ((unsigned short*)C)[(size_t)row * Cld + col] = f2bf(val);
        else
          ((float*)C)[(size_t)row * Cld + col] = val;
      }
    }
  }
}

// ---------------------------------------------------------------------------
// mega1 (208 blocks x 512 thr) — tiling as r12/r13.
// ---------------------------------------------------------------------------
__global__ __launch_bounds__(512) void mega1_k(const unsigned short* __restrict__ xrb,
                                               const unsigned short* __restrict__ w1cat,
                                               const unsigned short* __restrict__ wen,
                                               const unsigned short* __restrict__ w2t,
                                               unsigned short* __restrict__ H0p,
                                               unsigned short* __restrict__ W2EN) {
  const int bid = blockIdx.x;
  if (bid < 160) {
    const int p = bid >> 3, q = bid & 7;
    const int rt = q >> 2, ct = q & 3;
    const int MM[20] = {0,1,2,3, 0,1,2, 1,2,3, 0,1, 1,2, 2,3, 0,1,2,3};
    const int JJ[20] = {0,0,0,0, 1,1,1, 2,2,2, 3,3, 4,4, 5,5, 6,7,8,9};
    gemm_core<1, 0>(xrb, w1cat, H0p, nullptr, 2048, 512,
                    MM[p] * 512 + rt * 256, JJ[p] * 512 + ct * 128,
                    p * 512 + rt * 256, ct * 128);
  } else {
    const int b2 = bid - 160;
    const int s = b2 / 12, r = b2 % 12;
    const int rt = r >> 2, ct = r & 3;
    gemm_core<1, 0>(wen, w2t, W2EN, nullptr, 2048, 512,
                    rt * 256, s * 512 + ct * 128,
                    s * 768 + rt * 256, ct * 128);
  }
}

// gemmF: EN0 = h1(7680x512) @ W2EN_s^T + ENb_s   (fp32 out, 768 cols)
__global__ __launch_bounds__(512) void gemmF_k(const unsigned short* __restrict__ h1,
                                               const unsigned short* __restrict__ W2EN,
                                               const float* __restrict__ ENb,
                                               float* __restrict__ EN0) {
  const int y = blockIdx.y;                  // 0..29 row tiles of 256
  const int c = y >> 1;
  const int s = (c < 4) ? 1 : (c < 10) ? 2 : (c < 14) ? 3 : 4;
  gemm_core<0, 1>(h1, W2EN, EN0, ENb + (size_t)(s - 1) * 768, 512, 768,
                  y * 256, (s - 1) * 768 + blockIdx.x * 128,
                  y * 256, blockIdx.x * 128);
}

// ---------------------------------------------------------------------------
// prep_all (r13 proven): 5 prep bodies in one dispatch (17664 blocks).
// ---------------------------------------------------------------------------
__global__ __launch_bounds__(256) void prep_all_k(const float* __restrict__ x,
                                                  const float* w11, const float* w12,
                                                  const float* w13, const float* w14,
                                                  const float* w21, const float* w22,
                                                  const float* w23, const float* w24,
                                                  const float* __restrict__ wemb,
                                                  const float* __restrict__ wnode,
                                                  const float* b21, const float* b22,
                                                  const float* b23, const float* b24,
                                                  unsigned short* __restrict__ xrb,
                                                  unsigned short* __restrict__ w1cat,
                                                  unsigned short* __restrict__ w2t,
                                                  unsigned short* __restrict__ wen,
                                                  float* __restrict__ ENb) {
  __shared__ float lds[64][65];
  __shared__ float red[4][4];
  const int bid = blockIdx.x;
  if (bid < 10240) {                    // ---- w1cat
    const int tid = bid * 256 + threadIdx.x;
    const int r = tid >> 9;
    const int k = (tid & 511) << 2;
    const int j = r >> 9, o = r & 511;
    const float* src; int s, tt;
    if (j == 0)      { src = w11; s = 1; tt = 0; }
    else if (j < 3)  { src = w12; s = 2; tt = j - 1; }
    else if (j < 6)  { src = w13; s = 3; tt = j - 3; }
    else             { src = w14; s = 4; tt = j - 6; }
    const float4 vv = *(const float4*)(src + (size_t)o * (s * 2048) + tt * 2048 + k);
    ushort4 ov;
    ov.x = f2bf(vv.x); ov.y = f2bf(vv.y); ov.z = f2bf(vv.z); ov.w = f2bf(vv.w);
    *(ushort4*)(w1cat + (size_t)r * 2048 + k) = ov;
  } else if (bid < 14336) {             // ---- xr
    const int tid = (bid - 10240) * 256 + threadIdx.x;
    const int r = tid >> 9;
    const int k = (tid & 511) << 2;
    const int m = r >> 9, b = r & 511;
    const float4 vv = *(const float4*)(x + ((size_t)(b * 4 + m)) * 2048 + k);
    ushort4 o;
    o.x = f2bf(fmaxf(vv.x, 0.f)); o.y = f2bf(fmaxf(vv.y, 0.f));
    o.z = f2bf(fmaxf(vv.z, 0.f)); o.w = f2bf(fmaxf(vv.w, 0.f));
    *(ushort4*)(xrb + (size_t)r * 2048 + k) = o;
  } else if (bid < 15360) {             // ---- w2t
    const int idx = bid - 14336;
    const int s = idx >> 8, rem = idx & 255;
    const int rt = rem >> 3, ct = rem & 7;
    const float* src = (s == 0) ? w21 : (s == 1) ? w22 : (s == 2) ? w23 : w24;
    const int tr = threadIdx.x >> 4;
    const int tc = (threadIdx.x & 15) << 2;
#pragma unroll
    for (int i = 0; i < 4; ++i) {
      const float4 v = *(const float4*)(src + (size_t)(rt * 64 + tr + 16 * i) * 512 + ct * 64 + tc);
      lds[tr + 16 * i][tc + 0] = v.x; lds[tr + 16 * i][tc + 1] = v.y;
      lds[tr + 16 * i][tc + 2] = v.z; lds[tr + 16 * i][tc + 3] = v.w;
    }
    __syncthreads();
#pragma unroll
    for (int i = 0; i < 4; ++i) {
      ushort4 ov;
      ov.x = f2bf(lds[tc + 0][tr + 16 * i]); ov.y = f2bf(lds[tc + 1][tr + 16 * i]);
      ov.z = f2bf(lds[tc + 2][tr + 16 * i]); ov.w = f2bf(lds[tc + 3][tr + 16 * i]);
      *(ushort4*)(w2t + ((size_t)s * 512 + ct * 64 + tr + 16 * i) * 2048 + rt * 64 + tc) = ov;
    }
  } else if (bid < 16896) {             // ---- wen
    const int tid = (bid - 15360) * 256 + threadIdx.x;
    const int r = tid >> 9;
    const int k = (tid & 511) << 2;
    float4 vv = make_float4(0.f, 0.f, 0.f, 0.f);
    if (r < 300)       vv = *(const float4*)(wemb + (size_t)r * 2048 + k);
    else if (r < 691)  vv = *(const float4*)(wnode + (size_t)(r - 300) * 2048 + k);
    ushort4 ov;
    ov.x = f2bf(vv.x); ov.y = f2bf(vv.y); ov.z = f2bf(vv.z); ov.w = f2bf(vv.w);
    *(ushort4*)(wen + (size_t)r * 2048 + k) = ov;
  } else {                              // ---- enb v2
    const int e = bid - 16896;          // 0..767
    const int t8 = threadIdx.x << 3;
    float a0 = 0.f, a1 = 0.f, a2 = 0.f, a3 = 0.f;
    if (e < 691) {
      const float* row = (e < 300) ? (wemb + (size_t)e * 2048)
                                   : (wnode + (size_t)(e - 300) * 2048);
      const float4 r0 = *(const float4*)(row + t8);
      const float4 r1 = *(const float4*)(row + t8 + 4);
      const float4 c10 = *(const float4*)(b21 + t8), c11 = *(const float4*)(b21 + t8 + 4);
      const float4 c20 = *(const float4*)(b22 + t8), c21 = *(const float4*)(b22 + t8 + 4);
      const float4 c30 = *(const float4*)(b23 + t8), c31 = *(const float4*)(b23 + t8 + 4);
      const float4 c40 = *(const float4*)(b24 + t8), c41 = *(const float4*)(b24 + t8 + 4);
      a0 = r0.x*c10.x + r0.y*c10.y + r0.z*c10.z + r0.w*c10.w
         + r1.x*c11.x + r1.y*c11.y + r1.z*c11.z + r1.w*c11.w;
      a1 = r0.x*c20.x + r0.y*c20.y + r0.z*c20.z + r0.w*c20.w
         + r1.x*c21.x + r1.y*c21.y + r1.z*c21.z + r1.w*c21.w;
      a2 = r0.x*c30.x + r0.y*c30.y + r0.z*c30.z + r0.w*c30.w
         + r1.x*c31.x + r1.y*c31.y + r1.z*c31.z + r1.w*c31.w;
      a3 = r0.x*c40.x + r0.y*c40.y + r0.z*c40.z + r0.w*c40.w
         + r1.x*c41.x + r1.y*c41.y + r1.z*c41.z + r1.w*c41.w;
    }
#pragma unroll
    for (int off = 32; off; off >>= 1) {
      a0 += __shfl_down(a0, off); a1 += __shfl_down(a1, off);
      a2 += __shfl_down(a2, off); a3 += __shfl_down(a3, off);
    }
    const int wv = threadIdx.x >> 6;
    if ((threadIdx.x & 63) == 0) {
      red[wv][0] = a0; red[wv][1] = a1; red[wv][2] = a2; red[wv][3] = a3;
    }
    __syncthreads();
    if (threadIdx.x < 4) {
      const float v = red[0][threadIdx.x] + red[1][threadIdx.x] +
                      red[2][threadIdx.x] + red[3][threadIdx.x];
      ENb[(size_t)threadIdx.x * 768 + e] = (e < 691) ? v : 0.f;
    }
  }
}

// combine1 (round-5 proven)
__global__ __launch_bounds__(128) void combine1_k(const unsigned short* __restrict__ H0p,
                                                  unsigned short* __restrict__ h1,
                                                  const float* __restrict__ b11,
                                                  const float* __restrict__ b12,
                                                  const float* __restrict__ b13,
                                                  const float* __restrict__ b14) {
  const int cb = blockIdx.x;            // 0..7679 = c*512+b
  const int c = cb >> 9, b = cb & 511;
  const int s = (c < 4) ? 1 : (c < 10) ? 2 : (c < 14) ? 3 : 4;
  const unsigned char P[15][4] = {
    {0,0,0,0},{1,0,0,0},{2,0,0,0},{3,0,0,0},
    {4,7,0,0},{4,8,0,0},{4,9,0,0},{5,8,0,0},{5,9,0,0},{6,9,0,0},
    {10,12,14,0},{10,12,15,0},{10,13,15,0},{11,13,15,0},
    {16,17,18,19}};
  const float* b1 = (s == 1) ? b11 : (s == 2) ? b12 : (s == 3) ? b13 : b14;
  const int o = threadIdx.x << 2;
  float4 a = *(const float4*)(b1 + o);
  for (int t = 0; t < s; ++t) {
    const int p = P[c][t];
    const ushort4 hv = *(const ushort4*)(H0p + ((size_t)(p * 512 + b)) * 512 + o);
    a.x += bf2f(hv.x); a.y += bf2f(hv.y); a.z += bf2f(hv.z); a.w += bf2f(hv.w);
  }
  ushort4 ov;
  ov.x = f2bf(fmaxf(a.x, 0.f)); ov.y = f2bf(fmaxf(a.y, 0.f));
  ov.z = f2bf(fmaxf(a.z, 0.f)); ov.w = f2bf(fmaxf(a.w, 0.f));
  *(ushort4*)(h1 + (size_t)cb * 512 + o) = ov;
}

// combine2 (round-5 proven)
__global__ __launch_bounds__(256) void combine2_k(const float* __restrict__ EN0,
                                                  const float* __restrict__ b_emb,
                                                  const float* __restrict__ b_node,
                                                  float* __restrict__ out0,
                                                  float* __restrict__ out1) {
  const int b   = blockIdx.x;
  const int col = blockIdx.y * 256 + threadIdx.x;
  if (col >= 691) return;
  float vals[15];
#pragma unroll
  for (int j = 0; j < 15; ++j)
    vals[j] = EN0[((size_t)(j * 512 + b)) * 768 + col];
  const int MSK[15] = {1,2,4,8,3,5,9,6,10,12,7,11,13,14,15};
  if (col < 300) {
    const float be = b_emb[col];
#pragma unroll
    for (int i = 0; i < 15; ++i) {
      float sum = be;
#pragma unroll
      for (int j = 0; j < 15; ++j)
        if ((MSK[j] & MSK[i]) == MSK[j]) sum += vals[j];
      out0[((size_t)b * 15 + i) * 300 + col] = sum;
    }
  } else {
    const int v = col - 300;
    const float bn = b_node[v];
#pragma unroll
    for (int i = 0; i < 15; ++i) {
      float sum = bn;
#pragma unroll
      for (int j = 0; j < 15; ++j)
        if ((MSK[j] & MSK[i]) == MSK[j]) sum += vals[j];
      out1[((size_t)b * 391 + v) * 15 + i] = sum;
    }
  }
}

// ---------------------------------------------------------------------------
extern "C" void kernel_launch(void* const* d_in, const int* in_sizes, int n_in,
                              void* d_out, int out_size, void* d_ws, size_t ws_size,
                              hipStream_t stream) {
  const float* x     = (const float*)d_in[0];
  const float* w11   = (const float*)d_in[1];
  const float* b11   = (const float*)d_in[2];
  const float* w21   = (const float*)d_in[3];
  const float* b21   = (const float*)d_in[4];
  const float* w12   = (const float*)d_in[5];
  const float* b12   = (const float*)d_in[6];
  const float* w22   = (const float*)d_in[7];
  const float* b22   = (const float*)d_in[8];
  const float* w13   = (const float*)d_in[9];
  const float* b13   = (const float*)d_in[10];
  const float* w23   = (const float*)d_in[11];
  const float* b23   = (const float*)d_in[12];
  const float* w14   = (const float*)d_in[13];
  const float* b14   = (const float*)d_in[14];
  const float* w24   = (const float*)d_in[15];
  const float* b24   = (const float*)d_in[16];
  const float* wemb  = (const float*)d_in[17];
  const float* bemb  = (const float*)d_in[18];
  const float* wnode = (const float*)d_in[19];
  const float* bnode = (const float*)d_in[20];

  char* ws = (char*)d_ws;
  unsigned short* xrb   = (unsigned short*)(ws + 0);                 //  8,388,608
  unsigned short* w1cat = (unsigned short*)(ws + 8388608);           // -> 29,360,128
  unsigned short* w2t   = (unsigned short*)(ws + 29360128);          // -> 37,748,736
  unsigned short* wen   = (unsigned short*)(ws + 37748736);          // -> 40,894,464
  unsigned short* H0p   = (unsigned short*)(ws + 40894464);          // -> 51,380,224
  unsigned short* W2EN  = (unsigned short*)(ws + 51380224);          // -> 54,525,952
  float*          ENb   = (float*)(ws + 54525952);                   // -> 54,538,240
  unsigned short* h1bf  = (unsigned short*)(ws + 54538240);          // -> 62,402,560
  float*          EN0   = (float*)(ws + 0);                          // aliases xrb/w1cat

  float* out0 = (float*)d_out;            // embeddings (512,15,300)
  float* out1 = out0 + 2304000;           // node_out^T (512,391,15)

  prep_all_k<<<17664, 256, 0, stream>>>(x, w11, w12, w13, w14, w21, w22, w23, w24,
                                        wemb, wnode, b21, b22, b23, b24,
                                        xrb, w1cat, w2t, wen, ENb);
  mega1_k   <<<208, 512, 0, stream>>>(xrb, w1cat, wen, w2t, H0p, W2EN);
  combine1_k<<<7680, 128, 0, stream>>>(H0p, h1bf, b11, b12, b13, b14);
  gemmF_k   <<<dim3(6, 30), 512, 0, stream>>>(h1bf, W2EN, ENb, EN0);
  combine2_k<<<dim3(512, 3), 256, 0, stream>>>(EN0, bemb, bnode, out0, out1);
}

// Round 15
// 92.458 us; speedup vs baseline: 1.1455x; 1.1455x over previous
//
#include <hip/hip_runtime.h>
#include <stdint.h>

using bf16x8 = __attribute__((ext_vector_type(8))) short;
using f32x4  = __attribute__((ext_vector_type(4))) float;

#define DEVINL __device__ __forceinline__

DEVINL unsigned short f2bf(float f) {
  union { float f; unsigned u; } v; v.f = f;
  unsigned u = v.u;
  return (unsigned short)((u + 0x7FFFu + ((u >> 16) & 1u)) >> 16);
}
DEVINL float bf2f(unsigned short h) {
  union { unsigned u; float f; } v; v.u = ((unsigned)h) << 16;
  return v.f;
}

DEVINL void gload_lds16(const void* g, void* l) {
  __builtin_amdgcn_global_load_lds(
      (const __attribute__((address_space(1))) void*)g,
      (__attribute__((address_space(3))) void*)l, 16, 0, 0);
}

// ---------------------------------------------------------------------------
// m201-rhythm core at our quantum: 256x128 bf16 tile, 8 waves (4M x 2N),
// BK=64, 3-slot tile ring (144 KB LDS; 1 blk/CU as r12).
// Per K-tile 2 phases, each: {8 ds_read ; STAGE half (3 gloads) ; [vmcnt(6)
// in ph2 only, never 0 mid-loop] ; barrier ; setprio(1) 16 MFMA setprio(0) ;
// barrier}. ds_read latency hides under the phase barrier (m201's key).
// T2 XOR swizzle via pre-swizzled GLOBAL source (LDS dest linear; bank
// conflicts measured 0). Ring hazard: STAGE(kt+2)->slot (kt-1)%3 whose reads
// were lgkm-forced before kt-1's trailing barrier.
// A (row-major bf16, ld=K), B (row-major bf16, ld=K), C = A·B^T (+bias).
// ---------------------------------------------------------------------------
template<int OUT_BF16, int HAS_BIAS>
DEVINL void gemm_core(const unsigned short* __restrict__ A,
                      const unsigned short* __restrict__ B,
                      void* __restrict__ C,
                      const float* __restrict__ bias,
                      int K, int Cld, int arow0, int brow0, int crow0, int ccol0)
{
  __shared__ __align__(16) unsigned short As[3][256 * 64];   // 96 KB
  __shared__ __align__(16) unsigned short Bs[3][128 * 64];   // 48 KB

  const int t    = threadIdx.x;        // 0..511
  const int wave = t >> 6;             // 0..7
  const int lane = t & 63;
  const int wr   = (wave >> 1) << 6;   // 0,64,128,192
  const int wc   = (wave & 1) << 6;    // 0,64
  const int lrow = lane & 15;
  const int kg   = lane >> 4;          // 0..3

  f32x4 acc[4][4];
#pragma unroll
  for (int r = 0; r < 4; ++r)
#pragma unroll
    for (int q = 0; q < 4; ++q) acc[r][q] = (f32x4){0.f, 0.f, 0.f, 0.f};

  // staging (pre-swizzled global source chunk: chunk_phys = chunk ^ (row&7))
  const int srow = t >> 3;                                  // 0..63
  const int scol = (((t & 7) ^ (srow & 7)) << 3);
  const unsigned short* aSrc = A + (size_t)(arow0 + srow) * K + scol;
  const unsigned short* bSrc = B + (size_t)(brow0 + srow) * K + scol;

  // S0 = A rows [0,128) + B rows [0,64); S1 = A rows [128,256) + B rows [64,128)
  auto STAGE_S0 = [&](int slot, int kt) {
    const int k0 = kt << 6;
    char* aD = (char*)As[slot] + wave * 1024;
    char* bD = (char*)Bs[slot] + wave * 1024;
    gload_lds16(aSrc + (size_t)0 * K + k0, aD);
    gload_lds16(aSrc + (size_t)64 * K + k0, aD + 8192);
    gload_lds16(bSrc + (size_t)0 * K + k0, bD);
  };
  auto STAGE_S1 = [&](int slot, int kt) {
    const int k0 = kt << 6;
    char* aD = (char*)As[slot] + wave * 1024;
    char* bD = (char*)Bs[slot] + wave * 1024;
    gload_lds16(aSrc + (size_t)128 * K + k0, aD + 16384);
    gload_lds16(aSrc + (size_t)192 * K + k0, aD + 24576);
    gload_lds16(bSrc + (size_t)64 * K + k0, bD + 8192);
  };

  const int nt = K >> 6;               // >= 8 at all call sites
  STAGE_S0(0, 0); STAGE_S1(0, 0);
  if (nt > 1) { STAGE_S0(1, 1); STAGE_S1(1, 1); }

  // swizzled read chunk offsets: chunk = (kg + kk/8) ^ (row&7)
  const int rs = lrow & 7;
  const int cA0 = ((kg + 0) ^ rs) << 3;   // kk = 0
  const int cA1 = ((kg + 4) ^ rs) << 3;   // kk = 32

  // validate tile 0 before first reads
  if (nt > 1) { asm volatile("s_waitcnt vmcnt(6)" ::: "memory"); }
  else        { asm volatile("s_waitcnt vmcnt(0)" ::: "memory"); }
  __builtin_amdgcn_s_barrier();

  int sl = 0;                          // slot of tile kt
  for (int kt = 0; kt < nt; ++kt) {
    const unsigned short* Ab = As[sl];
    const unsigned short* Bb = Bs[sl];
    int s2 = sl + 2; if (s2 >= 3) s2 -= 3;   // slot for kt+2

    // ---------- phase 1: reads kk=0 ; stage S0(kt+2) ; bar ; MFMA ; bar
    bf16x8 af[4], bq[4];
#pragma unroll
    for (int r = 0; r < 4; ++r)
      af[r] = *(const bf16x8*)&Ab[(wr + r * 16 + lrow) * 64 + cA0];
#pragma unroll
    for (int q = 0; q < 4; ++q)
      bq[q] = *(const bf16x8*)&Bb[(wc + q * 16 + lrow) * 64 + cA0];
    if (kt + 2 < nt) STAGE_S0(s2, kt + 2);
    __builtin_amdgcn_s_barrier();
    __builtin_amdgcn_s_setprio(1);
#pragma unroll
    for (int r = 0; r < 4; ++r)
#pragma unroll
      for (int q = 0; q < 4; ++q)
        acc[r][q] = __builtin_amdgcn_mfma_f32_16x16x32_bf16(af[r], bq[q], acc[r][q], 0, 0, 0);
    __builtin_amdgcn_s_setprio(0);
    __builtin_amdgcn_s_barrier();

    // ---------- phase 2: reads kk=32 ; stage S1(kt+2) ; vmcnt ; bar ; MFMA ; bar
#pragma unroll
    for (int r = 0; r < 4; ++r)
      af[r] = *(const bf16x8*)&Ab[(wr + r * 16 + lrow) * 64 + cA1];
#pragma unroll
    for (int q = 0; q < 4; ++q)
      bq[q] = *(const bf16x8*)&Bb[(wc + q * 16 + lrow) * 64 + cA1];
    if (kt + 2 < nt) {
      STAGE_S1(s2, kt + 2);
      asm volatile("s_waitcnt vmcnt(6)" ::: "memory");   // kt+1 landed; kt+2 in flight
    } else if (kt + 1 < nt) {
      asm volatile("s_waitcnt vmcnt(0)" ::: "memory");   // drain kt+1 (tail)
    }
    __builtin_amdgcn_s_barrier();
    __builtin_amdgcn_s_setprio(1);
#pragma unroll
    for (int r = 0; r < 4; ++r)
#pragma unroll
      for (int q = 0; q < 4; ++q)
        acc[r][q] = __builtin_amdgcn_mfma_f32_16x16x32_bf16(af[r], bq[q], acc[r][q], 0, 0, 0);
    __builtin_amdgcn_s_setprio(0);
    __builtin_amdgcn_s_barrier();

    ++sl; if (sl == 3) sl = 0;
  }

  // epilogue: C/D layout col=lane&15, row=(lane>>4)*4+v  [m89/m91 verified]
#pragma unroll
  for (int r = 0; r < 4; ++r) {
#pragma unroll
    for (int q = 0; q < 4; ++q) {
      const int col = ccol0 + wc + q * 16 + lrow;
      const float bv = HAS_BIAS ? bias[col] : 0.f;
#pragma unroll
      for (int v = 0; v < 4; ++v) {
        const int row = crow0 + wr + r * 16 + (kg << 2) + v;
        const float val = acc[r][q][v] + bv;
        if (OUT_BF16)
          ((unsigned short*)C)[(size_t)row * Cld + col] = f2bf(val);
        else
          ((float*)C)[(size_t)row * Cld + col] = val;
      }
    }
  }
}

// ---------------------------------------------------------------------------
// mega1 (208 blocks x 512 thr) — tiling as r12/r13.
// ---------------------------------------------------------------------------
__global__ __launch_bounds__(512) void mega1_k(const unsigned short* __restrict__ xrb,
                                               const unsigned short* __restrict__ w1cat,
                                               const unsigned short* __restrict__ wen,
                                               const unsigned short* __restrict__ w2t,
                                               unsigned short* __restrict__ H0p,
                                               unsigned short* __restrict__ W2EN) {
  const int bid = blockIdx.x;
  if (bid < 160) {
    const int p = bid >> 3, q = bid & 7;
    const int rt = q >> 2, ct = q & 3;
    const int MM[20] = {0,1,2,3, 0,1,2, 1,2,3, 0,1, 1,2, 2,3, 0,1,2,3};
    const int JJ[20] = {0,0,0,0, 1,1,1, 2,2,2, 3,3, 4,4, 5,5, 6,7,8,9};
    gemm_core<1, 0>(xrb, w1cat, H0p, nullptr, 2048, 512,
                    MM[p] * 512 + rt * 256, JJ[p] * 512 + ct * 128,
                    p * 512 + rt * 256, ct * 128);
  } else {
    const int b2 = bid - 160;
    const int s = b2 / 12, r = b2 % 12;
    const int rt = r >> 2, ct = r & 3;
    gemm_core<1, 0>(wen, w2t, W2EN, nullptr, 2048, 512,
                    rt * 256, s * 512 + ct * 128,
                    s * 768 + rt * 256, ct * 128);
  }
}

// gemmF: EN0 = h1(7680x512) @ W2EN_s^T + ENb_s   (fp32 out, 768 cols)
__global__ __launch_bounds__(512) void gemmF_k(const unsigned short* __restrict__ h1,
                                               const unsigned short* __restrict__ W2EN,
                                               const float* __restrict__ ENb,
                                               float* __restrict__ EN0) {
  const int y = blockIdx.y;                  // 0..29 row tiles of 256
  const int c = y >> 1;
  const int s = (c < 4) ? 1 : (c < 10) ? 2 : (c < 14) ? 3 : 4;
  gemm_core<0, 1>(h1, W2EN, EN0, ENb + (size_t)(s - 1) * 768, 512, 768,
                  y * 256, (s - 1) * 768 + blockIdx.x * 128,
                  y * 256, blockIdx.x * 128);
}

// ---------------------------------------------------------------------------
// prep_all (r13 proven): 5 prep bodies in one dispatch (17664 blocks).
// ---------------------------------------------------------------------------
__global__ __launch_bounds__(256) void prep_all_k(const float* __restrict__ x,
                                                  const float* w11, const float* w12,
                                                  const float* w13, const float* w14,
                                                  const float* w21, const float* w22,
                                                  const float* w23, const float* w24,
                                                  const float* __restrict__ wemb,
                                                  const float* __restrict__ wnode,
                                                  const float* b21, const float* b22,
                                                  const float* b23, const float* b24,
                                                  unsigned short* __restrict__ xrb,
                                                  unsigned short* __restrict__ w1cat,
                                                  unsigned short* __restrict__ w2t,
                                                  unsigned short* __restrict__ wen,
                                                  float* __restrict__ ENb) {
  __shared__ float lds[64][65];
  __shared__ float red[4][4];
  const int bid = blockIdx.x;
  if (bid < 10240) {                    // ---- w1cat
    const int tid = bid * 256 + threadIdx.x;
    const int r = tid >> 9;
    const int k = (tid & 511) << 2;
    const int j = r >> 9, o = r & 511;
    const float* src; int s, tt;
    if (j == 0)      { src = w11; s = 1; tt = 0; }
    else if (j < 3)  { src = w12; s = 2; tt = j - 1; }
    else if (j < 6)  { src = w13; s = 3; tt = j - 3; }
    else             { src = w14; s = 4; tt = j - 6; }
    const float4 vv = *(const float4*)(src + (size_t)o * (s * 2048) + tt * 2048 + k);
    ushort4 ov;
    ov.x = f2bf(vv.x); ov.y = f2bf(vv.y); ov.z = f2bf(vv.z); ov.w = f2bf(vv.w);
    *(ushort4*)(w1cat + (size_t)r * 2048 + k) = ov;
  } else if (bid < 14336) {             // ---- xr
    const int tid = (bid - 10240) * 256 + threadIdx.x;
    const int r = tid >> 9;
    const int k = (tid & 511) << 2;
    const int m = r >> 9, b = r & 511;
    const float4 vv = *(const float4*)(x + ((size_t)(b * 4 + m)) * 2048 + k);
    ushort4 o;
    o.x = f2bf(fmaxf(vv.x, 0.f)); o.y = f2bf(fmaxf(vv.y, 0.f));
    o.z = f2bf(fmaxf(vv.z, 0.f)); o.w = f2bf(fmaxf(vv.w, 0.f));
    *(ushort4*)(xrb + (size_t)r * 2048 + k) = o;
  } else if (bid < 15360) {             // ---- w2t
    const int idx = bid - 14336;
    const int s = idx >> 8, rem = idx & 255;
    const int rt = rem >> 3, ct = rem & 7;
    const float* src = (s == 0) ? w21 : (s == 1) ? w22 : (s == 2) ? w23 : w24;
    const int tr = threadIdx.x >> 4;
    const int tc = (threadIdx.x & 15) << 2;
#pragma unroll
    for (int i = 0; i < 4; ++i) {
      const float4 v = *(const float4*)(src + (size_t)(rt * 64 + tr + 16 * i) * 512 + ct * 64 + tc);
      lds[tr + 16 * i][tc + 0] = v.x; lds[tr + 16 * i][tc + 1] = v.y;
      lds[tr + 16 * i][tc + 2] = v.z; lds[tr + 16 * i][tc + 3] = v.w;
    }
    __syncthreads();
#pragma unroll
    for (int i = 0; i < 4; ++i) {
      ushort4 ov;
      ov.x = f2bf(lds[tc + 0][tr + 16 * i]); ov.y = f2bf(lds[tc + 1][tr + 16 * i]);
      ov.z = f2bf(lds[tc + 2][tr + 16 * i]); ov.w = f2bf(lds[tc + 3][tr + 16 * i]);
      *(ushort4*)(w2t + ((size_t)s * 512 + ct * 64 + tr + 16 * i) * 2048 + rt * 64 + tc) = ov;
    }
  } else if (bid < 16896) {             // ---- wen
    const int tid = (bid - 15360) * 256 + threadIdx.x;
    const int r = tid >> 9;
    const int k = (tid & 511) << 2;
    float4 vv = make_float4(0.f, 0.f, 0.f, 0.f);
    if (r < 300)       vv = *(const float4*)(wemb + (size_t)r * 2048 + k);
    else if (r < 691)  vv = *(const float4*)(wnode + (size_t)(r - 300) * 2048 + k);
    ushort4 ov;
    ov.x = f2bf(vv.x); ov.y = f2bf(vv.y); ov.z = f2bf(vv.z); ov.w = f2bf(vv.w);
    *(ushort4*)(wen + (size_t)r * 2048 + k) = ov;
  } else {                              // ---- enb v2
    const int e = bid - 16896;          // 0..767
    const int t8 = threadIdx.x << 3;
    float a0 = 0.f, a1 = 0.f, a2 = 0.f, a3 = 0.f;
    if (e < 691) {
      const float* row = (e < 300) ? (wemb + (size_t)e * 2048)
                                   : (wnode + (size_t)(e - 300) * 2048);
      const float4 r0 = *(const float4*)(row + t8);
      const float4 r1 = *(const float4*)(row + t8 + 4);
      const float4 c10 = *(const float4*)(b21 + t8), c11 = *(const float4*)(b21 + t8 + 4);
      const float4 c20 = *(const float4*)(b22 + t8), c21 = *(const float4*)(b22 + t8 + 4);
      const float4 c30 = *(const float4*)(b23 + t8), c31 = *(const float4*)(b23 + t8 + 4);
      const float4 c40 = *(const float4*)(b24 + t8), c41 = *(const float4*)(b24 + t8 + 4);
      a0 = r0.x*c10.x + r0.y*c10.y + r0.z*c10.z + r0.w*c10.w
         + r1.x*c11.x + r1.y*c11.y + r1.z*c11.z + r1.w*c11.w;
      a1 = r0.x*c20.x + r0.y*c20.y + r0.z*c20.z + r0.w*c20.w
         + r1.x*c21.x + r1.y*c21.y + r1.z*c21.z + r1.w*c21.w;
      a2 = r0.x*c30.x + r0.y*c30.y + r0.z*c30.z + r0.w*c30.w
         + r1.x*c31.x + r1.y*c31.y + r1.z*c31.z + r1.w*c31.w;
      a3 = r0.x*c40.x + r0.y*c40.y + r0.z*c40.z + r0.w*c40.w
         + r1.x*c41.x + r1.y*c41.y + r1.z*c41.z + r1.w*c41.w;
    }
#pragma unroll
    for (int off = 32; off; off >>= 1) {
      a0 += __shfl_down(a0, off); a1 += __shfl_down(a1, off);
      a2 += __shfl_down(a2, off); a3 += __shfl_down(a3, off);
    }
    const int wv = threadIdx.x >> 6;
    if ((threadIdx.x & 63) == 0) {
      red[wv][0] = a0; red[wv][1] = a1; red[wv][2] = a2; red[wv][3] = a3;
    }
    __syncthreads();
    if (threadIdx.x < 4) {
      const float v = red[0][threadIdx.x] + red[1][threadIdx.x] +
                      red[2][threadIdx.x] + red[3][threadIdx.x];
      ENb[(size_t)threadIdx.x * 768 + e] = (e < 691) ? v : 0.f;
    }
  }
}

// combine1 (round-5 proven)
__global__ __launch_bounds__(128) void combine1_k(const unsigned short* __restrict__ H0p,
                                                  unsigned short* __restrict__ h1,
                                                  const float* __restrict__ b11,
                                                  const float* __restrict__ b12,
                                                  const float* __restrict__ b13,
                                                  const float* __restrict__ b14) {
  const int cb = blockIdx.x;            // 0..7679 = c*512+b
  const int c = cb >> 9, b = cb & 511;
  const int s = (c < 4) ? 1 : (c < 10) ? 2 : (c < 14) ? 3 : 4;
  const unsigned char P[15][4] = {
    {0,0,0,0},{1,0,0,0},{2,0,0,0},{3,0,0,0},
    {4,7,0,0},{4,8,0,0},{4,9,0,0},{5,8,0,0},{5,9,0,0},{6,9,0,0},
    {10,12,14,0},{10,12,15,0},{10,13,15,0},{11,13,15,0},
    {16,17,18,19}};
  const float* b1 = (s == 1) ? b11 : (s == 2) ? b12 : (s == 3) ? b13 : b14;
  const int o = threadIdx.x << 2;
  float4 a = *(const float4*)(b1 + o);
  for (int t = 0; t < s; ++t) {
    const int p = P[c][t];
    const ushort4 hv = *(const ushort4*)(H0p + ((size_t)(p * 512 + b)) * 512 + o);
    a.x += bf2f(hv.x); a.y += bf2f(hv.y); a.z += bf2f(hv.z); a.w += bf2f(hv.w);
  }
  ushort4 ov;
  ov.x = f2bf(fmaxf(a.x, 0.f)); ov.y = f2bf(fmaxf(a.y, 0.f));
  ov.z = f2bf(fmaxf(a.z, 0.f)); ov.w = f2bf(fmaxf(a.w, 0.f));
  *(ushort4*)(h1 + (size_t)cb * 512 + o) = ov;
}

// combine2 (round-5 proven)
__global__ __launch_bounds__(256) void combine2_k(const float* __restrict__ EN0,
                                                  const float* __restrict__ b_emb,
                                                  const float* __restrict__ b_node,
                                                  float* __restrict__ out0,
                                                  float* __restrict__ out1) {
  const int b   = blockIdx.x;
  const int col = blockIdx.y * 256 + threadIdx.x;
  if (col >= 691) return;
  float vals[15];
#pragma unroll
  for (int j = 0; j < 15; ++j)
    vals[j] = EN0[((size_t)(j * 512 + b)) * 768 + col];
  const int MSK[15] = {1,2,4,8,3,5,9,6,10,12,7,11,13,14,15};
  if (col < 300) {
    const float be = b_emb[col];
#pragma unroll
    for (int i = 0; i < 15; ++i) {
      float sum = be;
#pragma unroll
      for (int j = 0; j < 15; ++j)
        if ((MSK[j] & MSK[i]) == MSK[j]) sum += vals[j];
      out0[((size_t)b * 15 + i) * 300 + col] = sum;
    }
  } else {
    const int v = col - 300;
    const float bn = b_node[v];
#pragma unroll
    for (int i = 0; i < 15; ++i) {
      float sum = bn;
#pragma unroll
      for (int j = 0; j < 15; ++j)
        if ((MSK[j] & MSK[i]) == MSK[j]) sum += vals[j];
      out1[((size_t)b * 391 + v) * 15 + i] = sum;
    }
  }
}

// ---------------------------------------------------------------------------
extern "C" void kernel_launch(void* const* d_in, const int* in_sizes, int n_in,
                              void* d_out, int out_size, void* d_ws, size_t ws_size,
                              hipStream_t stream) {
  const float* x     = (const float*)d_in[0];
  const float* w11   = (const float*)d_in[1];
  const float* b11   = (const float*)d_in[2];
  const float* w21   = (const float*)d_in[3];
  const float* b21   = (const float*)d_in[4];
  const float* w12   = (const float*)d_in[5];
  const float* b12   = (const float*)d_in[6];
  const float* w22   = (const float*)d_in[7];
  const float* b22   = (const float*)d_in[8];
  const float* w13   = (const float*)d_in[9];
  const float* b13   = (const float*)d_in[10];
  const float* w23   = (const float*)d_in[11];
  const float* b23   = (const float*)d_in[12];
  const float* w14   = (const float*)d_in[13];
  const float* b14   = (const float*)d_in[14];
  const float* w24   = (const float*)d_in[15];
  const float* b24   = (const float*)d_in[16];
  const float* wemb  = (const float*)d_in[17];
  const float* bemb  = (const float*)d_in[18];
  const float* wnode = (const float*)d_in[19];
  const float* bnode = (const float*)d_in[20];

  char* ws = (char*)d_ws;
  unsigned short* xrb   = (unsigned short*)(ws + 0);                 //  8,388,608
  unsigned short* w1cat = (unsigned short*)(ws + 8388608);           // -> 29,360,128
  unsigned short* w2t   = (unsigned short*)(ws + 29360128);          // -> 37,748,736
  unsigned short* wen   = (unsigned short*)(ws + 37748736);          // -> 40,894,464
  unsigned short* H0p   = (unsigned short*)(ws + 40894464);          // -> 51,380,224
  unsigned short* W2EN  = (unsigned short*)(ws + 51380224);          // -> 54,525,952
  float*          ENb   = (float*)(ws + 54525952);                   // -> 54,538,240
  unsigned short* h1bf  = (unsigned short*)(ws + 54538240);          // -> 62,402,560
  float*          EN0   = (float*)(ws + 0);                          // aliases xrb/w1cat

  float* out0 = (float*)d_out;            // embeddings (512,15,300)
  float* out1 = out0 + 2304000;           // node_out^T (512,391,15)

  prep_all_k<<<17664, 256, 0, stream>>>(x, w11, w12, w13, w14, w21, w22, w23, w24,
                                        wemb, wnode, b21, b22, b23, b24,
                                        xrb, w1cat, w2t, wen, ENb);
  mega1_k   <<<208, 512, 0, stream>>>(xrb, w1cat, wen, w2t, H0p, W2EN);
  combine1_k<<<7680, 128, 0, stream>>>(H0p, h1bf, b11, b12, b13, b14);
  gemmF_k   <<<dim3(6, 30), 512, 0, stream>>>(h1bf, W2EN, ENb, EN0);
  combine2_k<<<dim3(512, 3), 256, 0, stream>>>(EN0, bemb, bnode, out0, out1);
}